// Round 3
// baseline (1165.226 us; speedup 1.0000x reference)
//
#include <hip/hip_runtime.h>

#define B_BATCH 8
#define SEQ 4096
#define D_MODEL 1024
#define D_STATE 64
#define EPS 1e-6f

#define T_CHUNK 256   // time steps per scan block (16 chunks)
#define WARM 64       // redundant warm-up; A<=0.7311 => 0.7311^64 ~ 2e-9
#define ROUND 16      // steps staged in LDS per round

typedef float f32x2 __attribute__((ext_vector_type(2)));

__device__ __forceinline__ float sigmoidf(float v) {
    return 1.0f / (1.0f + __expf(-v));
}

__device__ __forceinline__ f32x2 pk_mul(f32x2 a, f32x2 b) {
    f32x2 d;
    asm("v_pk_mul_f32 %0, %1, %2" : "=v"(d) : "v"(a), "v"(b));
    return d;
}
__device__ __forceinline__ f32x2 pk_fma(f32x2 a, f32x2 b, f32x2 c) {
    f32x2 d;
    asm("v_pk_fma_f32 %0, %1, %2, %3" : "=v"(d) : "v"(a), "v"(b), "v"(c));
    return d;
}

// ---------------------------------------------------------------------------
// Kernel 0: apply sigmoids, transpose B_w to [D][N]
// ---------------------------------------------------------------------------
__global__ __launch_bounds__(256) void prep_kernel(
    const float* __restrict__ A_raw, const float* __restrict__ B_w,
    const float* __restrict__ C_w, const float* __restrict__ gamma,
    float* __restrict__ As, float* __restrict__ Bt, float* __restrict__ Cs,
    float* __restrict__ gs) {
    int i = blockIdx.x * 256 + threadIdx.x;   // 0 .. D*N-1
    int d = i >> 6;
    int n = i & 63;
    As[i] = sigmoidf(A_raw[i]);               // [D][N]
    Cs[i] = sigmoidf(C_w[i]);                 // [D][N]
    Bt[i] = sigmoidf(B_w[n * D_MODEL + d]);   // Bt[d][n] = sigmoid(B_w[n][d])
    if (n == 0) gs[d] = sigmoidf(gamma[d]);
}

// ---------------------------------------------------------------------------
// Kernel 1: U[row][n] = sum_d x[row][d] * Bt[d][n]   (row = b*SEQ + t)
// ---------------------------------------------------------------------------
__device__ __forceinline__ void fma4(float av, const float4 bv, float* acc) {
    acc[0] = fmaf(av, bv.x, acc[0]);
    acc[1] = fmaf(av, bv.y, acc[1]);
    acc[2] = fmaf(av, bv.z, acc[2]);
    acc[3] = fmaf(av, bv.w, acc[3]);
}

__global__ __launch_bounds__(256) void u_gemm_kernel(
    const float* __restrict__ x, const float* __restrict__ Bt,
    float* __restrict__ U) {
    __shared__ float xs[64 * 68];
    __shared__ float Bs[64 * 64];
    const int tid = threadIdx.x;
    const int row0 = blockIdx.x * 64;
    const int tr = tid >> 4;
    const int tc = tid & 15;
    float acc[4][4] = {};

    for (int d0 = 0; d0 < D_MODEL; d0 += 64) {
#pragma unroll
        for (int i = 0; i < 4; ++i) {
            int f4 = i * 1024 + tid * 4;
            int r = f4 >> 6, c = f4 & 63;
            float4 v = *(const float4*)&x[(size_t)(row0 + r) * D_MODEL + d0 + c];
            *(float4*)&xs[r * 68 + c] = v;
        }
#pragma unroll
        for (int i = 0; i < 4; ++i) {
            int f4 = i * 1024 + tid * 4;
            *(float4*)&Bs[f4] = *(const float4*)&Bt[d0 * 64 + f4];
        }
        __syncthreads();
#pragma unroll
        for (int dd = 0; dd < 64; dd += 4) {
            float4 b0 = *(const float4*)&Bs[(dd + 0) * 64 + tc * 4];
            float4 b1 = *(const float4*)&Bs[(dd + 1) * 64 + tc * 4];
            float4 b2 = *(const float4*)&Bs[(dd + 2) * 64 + tc * 4];
            float4 b3 = *(const float4*)&Bs[(dd + 3) * 64 + tc * 4];
#pragma unroll
            for (int i = 0; i < 4; ++i) {
                float4 a = *(const float4*)&xs[(tr * 4 + i) * 68 + dd];
                fma4(a.x, b0, acc[i]);
                fma4(a.y, b1, acc[i]);
                fma4(a.z, b2, acc[i]);
                fma4(a.w, b3, acc[i]);
            }
        }
        __syncthreads();
    }
#pragma unroll
    for (int i = 0; i < 4; ++i) {
        float4 v = make_float4(acc[i][0], acc[i][1], acc[i][2], acc[i][3]);
        *(float4*)&U[(size_t)(row0 + tr * 4 + i) * 64 + tc * 4] = v;
    }
}

// ---------------------------------------------------------------------------
// Kernel 2: time-split scan, packed fp32.
// Block = (b, 64-d chunk, t-chunk of 256). 4 lanes per d, 16 n/lane.
// Warm-up WARM steps from h=0 (contraction kills the error).
// ---------------------------------------------------------------------------
__global__ __launch_bounds__(256, 6) void scan_kernel(
    const float* __restrict__ x, const float* __restrict__ U,
    const float* __restrict__ As, const float* __restrict__ Cs,
    float* __restrict__ yraw, float* __restrict__ hout) {
    __shared__ float Ulds[ROUND * 64];   // 4 KB
    __shared__ float xlds[ROUND * 64];   // 4 KB
    __shared__ float ylds[ROUND * 64];   // 4 KB
    const int tid = threadIdx.x;
    const int c = blockIdx.x & 15;                 // t-chunk
    const int d0 = ((blockIdx.x >> 4) & 15) * 64;  // d-chunk
    const int b = blockIdx.x >> 8;                 // batch
    const int g = tid >> 2;   // 0..63 -> d = d0+g
    const int l = tid & 3;    // 0..3  -> n = l*16 .. l*16+15
    const int d = d0 + g;

    f32x2 h2[8], a2[8], c2[8];
    {
        const f32x2* Ap = (const f32x2*)&As[d * 64 + l * 16];
        const f32x2* Cp = (const f32x2*)&Cs[d * 64 + l * 16];
#pragma unroll
        for (int k = 0; k < 8; ++k) {
            a2[k] = Ap[k];
            c2[k] = Cp[k];
            h2[k] = (f32x2){0.0f, 0.0f};
        }
    }

    const size_t xbase = (size_t)b * SEQ * D_MODEL;
    const size_t ubase = (size_t)b * SEQ * 64;
    const int t_main = c * T_CHUNK;
    const int t_begin = (c == 0) ? 0 : t_main - WARM;
    const int t_end = t_main + T_CHUNK;
    const int f4 = tid * 4;            // 0..1023
    const int stt = f4 >> 6;           // staging row
    const int sdd = f4 & 63;           // staging col

    for (int t0 = t_begin; t0 < t_end; t0 += ROUND) {
        // stage U round: ROUND x 64 (contiguous) and x round: ROUND x 64-d
        *(float4*)&Ulds[f4] = *(const float4*)&U[ubase + (size_t)t0 * 64 + f4];
        *(float4*)&xlds[f4] =
            *(const float4*)&x[xbase + (size_t)(t0 + stt) * D_MODEL + d0 + sdd];
        __syncthreads();

        const bool emit = (t0 >= t_main);
        if (emit) {
#pragma unroll
            for (int tt = 0; tt < ROUND; ++tt) {
                const f32x2* Up = (const f32x2*)&Ulds[tt * 64 + l * 16];
                float xt = xlds[tt * 64 + g];
                f32x2 xt2 = {xt, xt};
                f32x2 ya = {0.0f, 0.0f}, yb = {0.0f, 0.0f};
#pragma unroll
                for (int k = 0; k < 4; ++k) {
                    f32x2 inp = pk_mul(Up[k], xt2);
                    h2[k] = pk_fma(h2[k], a2[k], inp);
                    h2[k].x = __builtin_amdgcn_fmed3f(h2[k].x, 0.0f, 1.0f);
                    h2[k].y = __builtin_amdgcn_fmed3f(h2[k].y, 0.0f, 1.0f);
                    ya = pk_fma(h2[k], c2[k], ya);
                }
#pragma unroll
                for (int k = 4; k < 8; ++k) {
                    f32x2 inp = pk_mul(Up[k], xt2);
                    h2[k] = pk_fma(h2[k], a2[k], inp);
                    h2[k].x = __builtin_amdgcn_fmed3f(h2[k].x, 0.0f, 1.0f);
                    h2[k].y = __builtin_amdgcn_fmed3f(h2[k].y, 0.0f, 1.0f);
                    yb = pk_fma(h2[k], c2[k], yb);
                }
                float y = (ya.x + yb.x) + (ya.y + yb.y);
                y += __shfl_xor(y, 1);
                y += __shfl_xor(y, 2);
                if (l == 0) ylds[tt * 64 + g] = y;
            }
        } else {
#pragma unroll
            for (int tt = 0; tt < ROUND; ++tt) {
                const f32x2* Up = (const f32x2*)&Ulds[tt * 64 + l * 16];
                float xt = xlds[tt * 64 + g];
                f32x2 xt2 = {xt, xt};
#pragma unroll
                for (int k = 0; k < 8; ++k) {
                    f32x2 inp = pk_mul(Up[k], xt2);
                    h2[k] = pk_fma(h2[k], a2[k], inp);
                    h2[k].x = __builtin_amdgcn_fmed3f(h2[k].x, 0.0f, 1.0f);
                    h2[k].y = __builtin_amdgcn_fmed3f(h2[k].y, 0.0f, 1.0f);
                }
            }
        }
        __syncthreads();

        if (emit) {
            *(float4*)&yraw[xbase + (size_t)(t0 + stt) * D_MODEL + d0 + sdd] =
                *(const float4*)&ylds[f4];
        }
        // next round's staging is fenced by the post-stage __syncthreads()
    }

    if (c == (SEQ / T_CHUNK) - 1) {
        size_t hoff = ((size_t)b * D_MODEL + d) * 64 + l * 16;
#pragma unroll
        for (int k = 0; k < 4; ++k) {
            float4 v = make_float4(h2[2 * k].x, h2[2 * k].y,
                                   h2[2 * k + 1].x, h2[2 * k + 1].y);
            *(float4*)&hout[hoff + 4 * k] = v;
        }
    }
}

// ---------------------------------------------------------------------------
// Kernel 3: normalize, one wave per (b,t) row, no LDS/barrier.
// out = clip(g*y/(sum_d y + eps) + x, 0, 1)
// ---------------------------------------------------------------------------
__global__ __launch_bounds__(256) void norm_kernel(
    const float* __restrict__ x, const float* __restrict__ gs,
    float* __restrict__ y) {
    const int lane = threadIdx.x & 63;
    const size_t row = (size_t)blockIdx.x * 4 + (threadIdx.x >> 6);
    const size_t base = row * D_MODEL;

    float4 yv[4];
    float s = 0.0f;
#pragma unroll
    for (int k = 0; k < 4; ++k) {
        yv[k] = *(const float4*)&y[base + lane * 4 + k * 256];
        s += (yv[k].x + yv[k].y) + (yv[k].z + yv[k].w);
    }
#pragma unroll
    for (int off = 1; off < 64; off <<= 1) s += __shfl_xor(s, off);
    float inv = 1.0f / (s + EPS);

#pragma unroll
    for (int k = 0; k < 4; ++k) {
        float4 xv = *(const float4*)&x[base + lane * 4 + k * 256];
        float4 gv = *(const float4*)&gs[lane * 4 + k * 256];
        float4 o;
        o.x = __builtin_amdgcn_fmed3f(fmaf(gv.x * yv[k].x, inv, xv.x), 0.0f, 1.0f);
        o.y = __builtin_amdgcn_fmed3f(fmaf(gv.y * yv[k].y, inv, xv.y), 0.0f, 1.0f);
        o.z = __builtin_amdgcn_fmed3f(fmaf(gv.z * yv[k].z, inv, xv.z), 0.0f, 1.0f);
        o.w = __builtin_amdgcn_fmed3f(fmaf(gv.w * yv[k].w, inv, xv.w), 0.0f, 1.0f);
        *(float4*)&y[base + lane * 4 + k * 256] = o;
    }
}

// ---------------------------------------------------------------------------
extern "C" void kernel_launch(void* const* d_in, const int* in_sizes, int n_in,
                              void* d_out, int out_size, void* d_ws,
                              size_t ws_size, hipStream_t stream) {
    const float* x     = (const float*)d_in[0];
    const float* A_raw = (const float*)d_in[1];
    const float* B_w   = (const float*)d_in[2];
    const float* C_w   = (const float*)d_in[3];
    const float* gamma = (const float*)d_in[4];

    float* out  = (float*)d_out;
    float* yout = out;                                      // [B,S,D]
    float* hout = out + (size_t)B_BATCH * SEQ * D_MODEL;    // [B,D,N]

    float* ws = (float*)d_ws;
    float* As = ws;                  // 65536
    float* Bt = ws + 65536;          // 65536
    float* Cs = ws + 131072;         // 65536
    float* gs = ws + 196608;         // 1024
    float* U  = ws + 197632;         // B*SEQ*64 = 2097152

    prep_kernel<<<256, 256, 0, stream>>>(A_raw, B_w, C_w, gamma, As, Bt, Cs, gs);
    u_gemm_kernel<<<(B_BATCH * SEQ) / 64, 256, 0, stream>>>(x, Bt, U);
    scan_kernel<<<B_BATCH * 16 * (SEQ / T_CHUNK), 256, 0, stream>>>(
        x, U, As, Cs, yout, hout);
    norm_kernel<<<(B_BATCH * SEQ) / 4, 256, 0, stream>>>(x, gs, yout);
}